// Round 6
// baseline (274.249 us; speedup 1.0000x reference)
//
#include <hip/hip_runtime.h>

typedef __attribute__((ext_vector_type(8))) short short8;
typedef __attribute__((ext_vector_type(4))) float f32x4;

#define GLDS(gp, lp) __builtin_amdgcn_global_load_lds( \
    (const __attribute__((address_space(1))) void*)(gp), \
    (__attribute__((address_space(3))) void*)(lp), 16, 0, 0)

__device__ __forceinline__ unsigned short f2bf(float f){
    unsigned u = __float_as_uint(f);
    unsigned r = (u + 0x7fffu + ((u >> 16) & 1u)) >> 16;
    return (unsigned short)r;
}
__device__ __forceinline__ float bf2f(unsigned short s){
    return __uint_as_float(((unsigned)s) << 16);
}

// ---------------- init: cast weights to bf16 + zero stats ----------------
__global__ __launch_bounds__(256) void init_kernel(const float* __restrict__ W1, const float* __restrict__ W2,
                                                   unsigned short* __restrict__ W1c, unsigned short* __restrict__ W2c,
                                                   float* __restrict__ stats){
    int i = blockIdx.x * 256 + threadIdx.x;
    if (i < 98304) W1c[i] = f2bf(W1[i]);
    if (i < 32768) W2c[i] = f2bf(W2[i]);
    if (i < 768) stats[i] = 0.f;
}

// ---------------- KNN (3-NN) — t = c^2 - 2 q.c (q^2 rank-invariant), branchy insert ----------------
__global__ __launch_bounds__(256) void knn_kernel(const float* __restrict__ xyz1, const float* __restrict__ xyz2,
                                                  int* __restrict__ oi, float* __restrict__ ow){
    __shared__ float sx[2048], sy[2048], sz[2048];
    __shared__ float sd[64][25];
    __shared__ int   si[64][25];
    int blk = blockIdx.x;
    int b  = blk >> 7;
    int n0 = (blk & 127) << 6;
    const float* p2 = xyz2 + (size_t)b * 2048 * 3;
    for (int j = threadIdx.x; j < 2048; j += 256){
        sx[j] = p2[j*3+0]; sy[j] = p2[j*3+1]; sz[j] = p2[j*3+2];
    }
    __syncthreads();
    int pp = threadIdx.x & 31, sub = threadIdx.x >> 5;
    int pA = n0 + pp;
    const float* qa = xyz1 + ((size_t)b * 8192 + pA) * 3;
    float ax = qa[0], ay = qa[1], az = qa[2];
    float bx = qa[96], by = qa[97], bz = qa[98];   // point pA+32
    float nax = -2.f*ax, nay = -2.f*ay, naz = -2.f*az;
    float nbx = -2.f*bx, nby = -2.f*by, nbz = -2.f*bz;
    float A0 = 1e30f, A1 = 1e30f, A2 = 1e30f; int Ai0 = 0, Ai1 = 0, Ai2 = 0;
    float B0 = 1e30f, B1 = 1e30f, B2 = 1e30f; int Bi0 = 0, Bi1 = 0, Bi2 = 0;
    int jb = sub << 8;
#pragma unroll 2
    for (int i = 0; i < 256; i += 4){
        f32x4 cx = *(const f32x4*)&sx[jb + i];
        f32x4 cy = *(const f32x4*)&sy[jb + i];
        f32x4 cz = *(const f32x4*)&sz[jb + i];
#pragma unroll
        for (int u = 0; u < 4; ++u){
            int j = jb + i + u;
            float c2 = fmaf(cx[u], cx[u], fmaf(cy[u], cy[u], cz[u]*cz[u]));
            float tA = fmaf(nax, cx[u], fmaf(nay, cy[u], fmaf(naz, cz[u], c2)));
            float tB = fmaf(nbx, cx[u], fmaf(nby, cy[u], fmaf(nbz, cz[u], c2)));
            if (tA < A2){
                if (tA < A1){
                    A2 = A1; Ai2 = Ai1;
                    if (tA < A0){ A1 = A0; Ai1 = Ai0; A0 = tA; Ai0 = j; }
                    else        { A1 = tA; Ai1 = j; }
                } else { A2 = tA; Ai2 = j; }
            }
            if (tB < B2){
                if (tB < B1){
                    B2 = B1; Bi2 = Bi1;
                    if (tB < B0){ B1 = B0; Bi1 = Bi0; B0 = tB; Bi0 = j; }
                    else        { B1 = tB; Bi1 = j; }
                } else { B2 = tB; Bi2 = j; }
            }
        }
    }
    int c = sub * 3;
    sd[pp][c] = A0; sd[pp][c+1] = A1; sd[pp][c+2] = A2;
    si[pp][c] = Ai0; si[pp][c+1] = Ai1; si[pp][c+2] = Ai2;
    sd[pp+32][c] = B0; sd[pp+32][c+1] = B1; sd[pp+32][c+2] = B2;
    si[pp+32][c] = Bi0; si[pp+32][c+1] = Bi1; si[pp+32][c+2] = Bi2;
    __syncthreads();
    if (threadIdx.x < 64){
        int lp = threadIdx.x;
        float d0 = 1e30f, d1 = 1e30f, d2 = 1e30f;
        int i0 = 0, i1 = 0, i2 = 0;
#pragma unroll
        for (int k = 0; k < 24; ++k){
            float d = sd[lp][k]; int j = si[lp][k];
            if (d < d2){
                if (d < d1){
                    d2 = d1; i2 = i1;
                    if (d < d0){ d1 = d0; i1 = i0; d0 = d; i0 = j; }
                    else        { d1 = d;  i1 = j; }
                } else { d2 = d; i2 = j; }
            }
        }
        const float* q = xyz1 + ((size_t)b * 8192 + n0 + lp) * 3;
        float q2 = fmaf(q[0], q[0], fmaf(q[1], q[1], q[2]*q[2]));
        float e0 = fmaxf(q2 + d0, 0.f), e1 = fmaxf(q2 + d1, 0.f), e2 = fmaxf(q2 + d2, 0.f);
        float w0 = 1.f / fmaxf(sqrtf(e0), 1e-8f);
        float w1 = 1.f / fmaxf(sqrtf(e1), 1e-8f);
        float w2 = 1.f / fmaxf(sqrtf(e2), 1e-8f);
        float inv = 1.f / (w0 + w1 + w2);
        int n = n0 + lp;
        size_t pbase = ((size_t)b * 8192 + n) * 3;
        ow[pbase + 0] = w0 * inv; ow[pbase + 1] = w1 * inv; ow[pbase + 2] = w2 * inv;
        oi[pbase + 0] = i0;       oi[pbase + 1] = i1;       oi[pbase + 2] = i2;
    }
}

// ---------------- feats2 (B,C2,N2) f32 -> f2t (B,N2,C2) bf16 ----------------
__global__ __launch_bounds__(256) void transpose_f2_kernel(const float* __restrict__ f2, unsigned short* __restrict__ f2t){
    __shared__ float tile[32][33];
    int b = blockIdx.z, c0 = blockIdx.y * 32, n0 = blockIdx.x * 32;
    int tx = threadIdx.x, ty = threadIdx.y;
    for (int i = 0; i < 32; i += 8)
        tile[ty + i][tx] = f2[((size_t)b * 256 + c0 + ty + i) * 2048 + n0 + tx];
    __syncthreads();
    for (int i = 0; i < 32; i += 8)
        f2t[((size_t)b * 2048 + n0 + ty + i) * 256 + c0 + tx] = f2bf(tile[tx][ty + i]);
}

// ---------------- feats1 (B,C1,N1) f32 -> f1t[p][128] bf16 (compact) ----------------
__global__ __launch_bounds__(256) void transpose_f1_kernel(const float* __restrict__ f1, unsigned short* __restrict__ f1t){
    __shared__ float tile[32][33];
    int b = blockIdx.z, c0 = blockIdx.y * 32, n0 = blockIdx.x * 32;
    int tx = threadIdx.x, ty = threadIdx.y;
    for (int i = 0; i < 32; i += 8)
        tile[ty + i][tx] = f1[((size_t)b * 128 + c0 + ty + i) * 8192 + n0 + tx];
    __syncthreads();
    for (int i = 0; i < 32; i += 8)
        f1t[((size_t)b * 8192 + n0 + ty + i) * 128 + c0 + tx] = f2bf(tile[tx][ty + i]);
}

// ---------------- GEMM1 fused v2: M-tile 64, N=256, K=384; full dbuf, 1 barrier/iter ----------------
// grid 1024; 4 waves, each 64 rows x 64 cols (acc[4][4]); gather for kt+1 issued before MFMA kt.
__global__ __launch_bounds__(256, 3) void gemm1_fused(const unsigned short* __restrict__ f2t,
                                                      const unsigned short* __restrict__ f1t,
                                                      const int* __restrict__ ki, const float* __restrict__ kw,
                                                      const unsigned short* __restrict__ W1c,
                                                      const float* __restrict__ bias,
                                                      unsigned short* __restrict__ h1,
                                                      float* __restrict__ gsum, float* __restrict__ gsq){
    __shared__ unsigned short As[2][64 * 40];
    __shared__ unsigned short Bs[2][256 * 32];
    __shared__ int   sIdx[192];
    __shared__ float sW[192];
    __shared__ float sLs[256], sLq[256];
    int tid = threadIdx.x;
    int m0 = blockIdx.x << 6;
    int b  = m0 >> 13;
    if (tid < 192){ sIdx[tid] = ki[(size_t)m0 * 3 + tid]; sW[tid] = kw[(size_t)m0 * 3 + tid]; }
    sLs[tid] = 0.f; sLq[tid] = 0.f;
    __syncthreads();

    int pt = tid >> 2, qq = tid & 3;
    int i0 = sIdx[pt*3], i1 = sIdx[pt*3+1], i2 = sIdx[pt*3+2];
    float w0 = sW[pt*3], w1 = sW[pt*3+1], w2 = sW[pt*3+2];
    const unsigned short* r0 = f2t + (((size_t)b * 2048 + i0) << 8) + qq * 8;
    const unsigned short* r1 = f2t + (((size_t)b * 2048 + i1) << 8) + qq * 8;
    const unsigned short* r2 = f2t + (((size_t)b * 2048 + i2) << 8) + qq * 8;
    const unsigned short* f1row = f1t + ((size_t)(m0 + pt) << 7) + qq * 8;
    const char* Bb = (const char*)W1c + (size_t)(tid >> 2) * 768 + (size_t)(tid & 3) * 16;

    int lane = tid & 63, wid = tid >> 6;
    int n_w = wid * 64;
    int lr = lane & 15, lq = lane >> 4;
    f32x4 acc[4][4] = {};

    auto interp3 = [&](uint4 a, uint4 c, uint4 d) -> uint4 {
        uint4 o;
        const unsigned* ap = (const unsigned*)&a; const unsigned* cp = (const unsigned*)&c;
        const unsigned* dp = (const unsigned*)&d; unsigned* op = (unsigned*)&o;
#pragma unroll
        for (int u = 0; u < 4; ++u){
            float lo = w0 * bf2f((unsigned short)(ap[u] & 0xffff))
                     + w1 * bf2f((unsigned short)(cp[u] & 0xffff))
                     + w2 * bf2f((unsigned short)(dp[u] & 0xffff));
            float hi = w0 * bf2f((unsigned short)(ap[u] >> 16))
                     + w1 * bf2f((unsigned short)(cp[u] >> 16))
                     + w2 * bf2f((unsigned short)(dp[u] >> 16));
            op[u] = (unsigned)f2bf(lo) | ((unsigned)f2bf(hi) << 16);
        }
        return o;
    };

    // prologue: stage kt=0
    {
        uint4 a = *(const uint4*)r0, c = *(const uint4*)r1, d = *(const uint4*)r2;
        *(uint4*)(&As[0][pt * 40 + qq * 8]) = interp3(a, c, d);
#pragma unroll
        for (int cc = 0; cc < 4; ++cc)
            GLDS(Bb + (size_t)cc * 49152, (char*)Bs[0] + cc * 4096 + tid * 16);
    }
    __syncthreads();

    for (int kt = 0; kt < 12; ++kt){
        int cur = kt & 1;
        uint4 pa, pc, pd;
        bool hasNext = kt < 11;
        int nk = kt + 1;
        if (hasNext){
            if (nk < 8){
                pa = *(const uint4*)(r0 + nk * 32);
                pc = *(const uint4*)(r1 + nk * 32);
                pd = *(const uint4*)(r2 + nk * 32);
            } else {
                pa = *(const uint4*)(f1row + (nk - 8) * 32);
            }
#pragma unroll
            for (int cc = 0; cc < 4; ++cc)
                GLDS(Bb + (size_t)cc * 49152 + nk * 64, (char*)Bs[cur ^ 1] + cc * 4096 + tid * 16);
        }
        short8 af[4], bfr[4];
#pragma unroll
        for (int mf = 0; mf < 4; ++mf)
            af[mf] = *(const short8*)(&As[cur][(mf * 16 + lr) * 40 + lq * 8]);
#pragma unroll
        for (int nf = 0; nf < 4; ++nf)
            bfr[nf] = *(const short8*)(&Bs[cur][(n_w + nf * 16 + lr) * 32 + lq * 8]);
#pragma unroll
        for (int mf = 0; mf < 4; ++mf)
#pragma unroll
            for (int nf = 0; nf < 4; ++nf)
                acc[mf][nf] = __builtin_amdgcn_mfma_f32_16x16x32_bf16(af[mf], bfr[nf], acc[mf][nf], 0, 0, 0);
        if (hasNext){
            uint4 o = (nk < 8) ? interp3(pa, pc, pd) : pa;
            *(uint4*)(&As[cur ^ 1][pt * 40 + qq * 8]) = o;
        }
        __syncthreads();
    }

    // BN stats
    float bv[4];
#pragma unroll
    for (int nf = 0; nf < 4; ++nf) bv[nf] = bias[n_w + nf * 16 + lr];
#pragma unroll
    for (int nf = 0; nf < 4; ++nf){
        float ps = 0.f, pq = 0.f;
#pragma unroll
        for (int mf = 0; mf < 4; ++mf)
#pragma unroll
            for (int r = 0; r < 4; ++r){
                float v = acc[mf][nf][r] + bv[nf];
                ps += v; pq += v * v;
            }
        ps += __shfl_xor(ps, 16); ps += __shfl_xor(ps, 32);
        pq += __shfl_xor(pq, 16); pq += __shfl_xor(pq, 32);
        if (lq == 0){ atomicAdd(&sLs[n_w + nf * 16 + lr], ps); atomicAdd(&sLq[n_w + nf * 16 + lr], pq); }
    }
    // store (nf-inner: contiguous 128B runs per 16-lane group)
#pragma unroll
    for (int mf = 0; mf < 4; ++mf)
#pragma unroll
        for (int r = 0; r < 4; ++r){
            size_t rb = (size_t)(m0 + mf * 16 + lq * 4 + r) * 256 + n_w + lr;
#pragma unroll
            for (int nf = 0; nf < 4; ++nf)
                h1[rb + nf * 16] = f2bf(acc[mf][nf][r] + bv[nf]);
        }
    __syncthreads();
    atomicAdd(&gsum[tid], sLs[tid]);
    atomicAdd(&gsq[tid],  sLq[tid]);
}

// ---------------- BN1 scale/shift prep ----------------
__global__ void bnprep_kernel(const float* __restrict__ s1, const float* __restrict__ q1,
                              const float* __restrict__ g1, const float* __restrict__ be1,
                              float* __restrict__ sc, float* __restrict__ sh){
    int c = threadIdx.x;
    const float inv = 1.0f / 65536.0f;
    float m = s1[c] * inv;
    float v = q1[c] * inv - m * m;
    float rs = rsqrtf(v + 1e-5f);
    float s = g1[c] * rs;
    sc[c] = s; sh[c] = be1[c] - m * s;
}

// ---------------- GEMM2 fused v2: A = BN1+ReLU(h1); M-tile 64, N=128, K=256; dbuf, 1 barrier ----------------
__global__ __launch_bounds__(256, 4) void gemm2_fused(const unsigned short* __restrict__ h1,
                                                      const unsigned short* __restrict__ W2c,
                                                      const float* __restrict__ bias,
                                                      const float* __restrict__ sc1, const float* __restrict__ sh1,
                                                      float* __restrict__ h2,
                                                      float* __restrict__ gsum, float* __restrict__ gsq){
    __shared__ unsigned short As[2][64 * 40];
    __shared__ unsigned short Bs[2][128 * 32];
    __shared__ float ssc[256], ssh[256];
    __shared__ float sLs[128], sLq[128];
    int tid = threadIdx.x;
    int m0 = blockIdx.x << 6;
    ssc[tid] = sc1[tid]; ssh[tid] = sh1[tid];
    if (tid < 128){ sLs[tid] = 0.f; sLq[tid] = 0.f; }
    __syncthreads();

    int pt = tid >> 2, qq = tid & 3;
    const unsigned short* hrow = h1 + ((size_t)(m0 + pt) << 8) + qq * 8;
    const char* Bb = (const char*)W2c + (size_t)(tid >> 2) * 512 + (size_t)(tid & 3) * 16;

    int lane = tid & 63, wid = tid >> 6;
    int n_w = wid * 32;
    int lr = lane & 15, lq = lane >> 4;
    f32x4 acc[4][2] = {};

    auto bnrelu = [&](uint4 v, int cb) -> uint4 {
        uint4 o;
        const unsigned* vp = (const unsigned*)&v; unsigned* op = (unsigned*)&o;
#pragma unroll
        for (int u = 0; u < 4; ++u){
            int cc = cb + 2 * u;
            float lo = fmaxf(bf2f((unsigned short)(vp[u] & 0xffff)) * ssc[cc]     + ssh[cc],     0.f);
            float hi = fmaxf(bf2f((unsigned short)(vp[u] >> 16))    * ssc[cc + 1] + ssh[cc + 1], 0.f);
            op[u] = (unsigned)f2bf(lo) | ((unsigned)f2bf(hi) << 16);
        }
        return o;
    };

    {
        uint4 v = *(const uint4*)hrow;
        *(uint4*)(&As[0][pt * 40 + qq * 8]) = bnrelu(v, qq * 8);
#pragma unroll
        for (int cc = 0; cc < 2; ++cc)
            GLDS(Bb + (size_t)cc * 32768, (char*)Bs[0] + cc * 4096 + tid * 16);
    }
    __syncthreads();

    for (int kt = 0; kt < 8; ++kt){
        int cur = kt & 1;
        uint4 pv;
        bool hasNext = kt < 7;
        int nk = kt + 1;
        if (hasNext){
            pv = *(const uint4*)(hrow + nk * 32);
#pragma unroll
            for (int cc = 0; cc < 2; ++cc)
                GLDS(Bb + (size_t)cc * 32768 + nk * 64, (char*)Bs[cur ^ 1] + cc * 4096 + tid * 16);
        }
        short8 af[4], bfr[2];
#pragma unroll
        for (int mf = 0; mf < 4; ++mf)
            af[mf] = *(const short8*)(&As[cur][(mf * 16 + lr) * 40 + lq * 8]);
#pragma unroll
        for (int nf = 0; nf < 2; ++nf)
            bfr[nf] = *(const short8*)(&Bs[cur][(n_w + nf * 16 + lr) * 32 + lq * 8]);
#pragma unroll
        for (int mf = 0; mf < 4; ++mf)
#pragma unroll
            for (int nf = 0; nf < 2; ++nf)
                acc[mf][nf] = __builtin_amdgcn_mfma_f32_16x16x32_bf16(af[mf], bfr[nf], acc[mf][nf], 0, 0, 0);
        if (hasNext)
            *(uint4*)(&As[cur ^ 1][pt * 40 + qq * 8]) = bnrelu(pv, nk * 32 + qq * 8);
        __syncthreads();
    }

    float bv[2];
#pragma unroll
    for (int nf = 0; nf < 2; ++nf) bv[nf] = bias[n_w + nf * 16 + lr];
#pragma unroll
    for (int nf = 0; nf < 2; ++nf){
        float ps = 0.f, pq = 0.f;
#pragma unroll
        for (int mf = 0; mf < 4; ++mf)
#pragma unroll
            for (int r = 0; r < 4; ++r){
                float v = acc[mf][nf][r] + bv[nf];
                ps += v; pq += v * v;
            }
        ps += __shfl_xor(ps, 16); ps += __shfl_xor(ps, 32);
        pq += __shfl_xor(pq, 16); pq += __shfl_xor(pq, 32);
        if (lq == 0){ atomicAdd(&sLs[n_w + nf * 16 + lr], ps); atomicAdd(&sLq[n_w + nf * 16 + lr], pq); }
    }
#pragma unroll
    for (int mf = 0; mf < 4; ++mf)
#pragma unroll
        for (int r = 0; r < 4; ++r){
            size_t rb = (size_t)(m0 + mf * 16 + lq * 4 + r) * 128 + n_w + lr;
#pragma unroll
            for (int nf = 0; nf < 2; ++nf)
                h2[rb + nf * 16] = acc[mf][nf][r] + bv[nf];
        }
    __syncthreads();
    if (tid < 128){
        atomicAdd(&gsum[tid], sLs[tid]);
        atomicAdd(&gsq[tid],  sLq[tid]);
    }
}

// ---------------- BN+ReLU on h2 + transpose (p,o)->(b,o,n) f32 out ----------------
__global__ __launch_bounds__(256) void bn2_transpose_kernel(const float* __restrict__ h2, const float* __restrict__ gsum,
                                                            const float* __restrict__ gsq, const float* __restrict__ g2,
                                                            const float* __restrict__ be2, float* __restrict__ out){
    __shared__ float tile[32][33];
    const float inv = 1.0f / 65536.0f;
    int b = blockIdx.z, o0 = blockIdx.y * 32, n0 = blockIdx.x * 32;
    int tx = threadIdx.x, ty = threadIdx.y;
    for (int i = 0; i < 32; i += 8)
        tile[ty + i][tx] = h2[((size_t)b * 8192 + n0 + ty + i) * 128 + o0 + tx];
    __syncthreads();
    for (int i = 0; i < 32; i += 8){
        int ch = o0 + ty + i;
        float m = gsum[ch] * inv;
        float va = gsq[ch] * inv - m * m;
        float rs = rsqrtf(va + 1e-5f);
        float sc = g2[ch] * rs, sh = be2[ch] - m * sc;
        float v = fmaxf(tile[tx][ty + i] * sc + sh, 0.f);
        out[((size_t)b * 128 + ch) * 8192 + n0 + tx] = v;
    }
}

extern "C" void kernel_launch(void* const* d_in, const int* in_sizes, int n_in,
                              void* d_out, int out_size, void* d_ws, size_t ws_size,
                              hipStream_t stream){
    const float* xyz1   = (const float*)d_in[0];
    const float* xyz2   = (const float*)d_in[1];
    const float* feats1 = (const float*)d_in[2];
    const float* feats2 = (const float*)d_in[3];
    const float* W1  = (const float*)d_in[4];
    const float* b1  = (const float*)d_in[5];
    const float* g1  = (const float*)d_in[6];
    const float* be1 = (const float*)d_in[7];
    const float* W2  = (const float*)d_in[8];
    const float* b2  = (const float*)d_in[9];
    const float* g2  = (const float*)d_in[10];
    const float* be2 = (const float*)d_in[11];
    float* out = (float*)d_out;

    char* p = (char*)d_ws;
    auto take = [&](size_t bytes) -> char* {
        char* r = p; p += (bytes + 255) & ~(size_t)255; return r;
    };
    unsigned short* W1c = (unsigned short*)take((size_t)98304 * 2);
    unsigned short* W2c = (unsigned short*)take((size_t)32768 * 2);
    int*   ki    = (int*)take((size_t)65536 * 3 * 4);
    float* kw    = (float*)take((size_t)65536 * 3 * 4);
    float* stats = (float*)take(768 * 4);
    float* scsh  = (float*)take(512 * 4);
    unsigned short* f2t = (unsigned short*)take((size_t)8 * 2048 * 256 * 2);
    unsigned short* f1t = (unsigned short*)take((size_t)65536 * 128 * 2);
    unsigned short* h1  = (unsigned short*)take((size_t)65536 * 256 * 2);
    float* h2 = (float*)take((size_t)65536 * 128 * 4);

    float* s1 = stats, *q1 = stats + 256, *s2 = stats + 512, *q2 = stats + 640;
    float* sc1 = scsh, *sh1 = scsh + 256;

    init_kernel<<<dim3(384), 256, 0, stream>>>(W1, W2, W1c, W2c, stats);
    knn_kernel<<<dim3(1024), 256, 0, stream>>>(xyz1, xyz2, ki, kw);
    transpose_f2_kernel<<<dim3(64, 8, 8), dim3(32, 8), 0, stream>>>(feats2, f2t);
    transpose_f1_kernel<<<dim3(256, 4, 8), dim3(32, 8), 0, stream>>>(feats1, f1t);
    gemm1_fused<<<dim3(1024), 256, 0, stream>>>(f2t, f1t, ki, kw, W1c, b1, h1, s1, q1);
    bnprep_kernel<<<dim3(1), 256, 0, stream>>>(s1, q1, g1, be1, sc1, sh1);
    gemm2_fused<<<dim3(1024), 256, 0, stream>>>(h1, W2c, b2, sc1, sh1, h2, s2, q2);
    bn2_transpose_kernel<<<dim3(256, 4, 8), dim3(32, 8), 0, stream>>>(h2, s2, q2, g2, be2, out);
}